// Round 2
// baseline (907.266 us; speedup 1.0000x reference)
//
#include <hip/hip_runtime.h>
#include <stdint.h>

using u8  = unsigned char;
using u16 = unsigned short;
using u32 = unsigned int;

typedef __bf16 bf16x8 __attribute__((ext_vector_type(8)));
typedef float  f32x4  __attribute__((ext_vector_type(4)));

__device__ __forceinline__ float b2f(u16 u) {
    union { u32 i; float f; } v; v.i = ((u32)u) << 16; return v.f;
}
__device__ __forceinline__ u16 f2bf(float f) {
    union { float f; u32 i; } v; v.f = f;
    u32 u = v.i;
    return (u16)((u + 0x7FFFu + ((u >> 16) & 1u)) >> 16);
}

// ws layout: int flags[2] at base (dtype: 0=bf16 1=f32 ; mask width: 0=4B 1=2B 2=1B)
// padded masked bf16 weights start at (u16*)ws + WS_OFF
#define WS_OFF 256
#define OFF_W1 0
#define OFF_W2 1048576
#define OFF_W3 1966080
#define OFF_W4 2392064
#define PS1 1048576
#define PS2 917504
#define PS3 425984
#define PS4 286720

// ---------------- dtype / mask-width detection -----------------------------
__global__ void detect_kernel(int* __restrict__ flags,
                              const u32* __restrict__ xw,
                              const u32* __restrict__ mw) {
    const int lane = threadIdx.x;   // 64 threads
    int outl = 0;
#pragma unroll
    for (int i = 0; i < 4; ++i) {
        u32 u = xw[lane * 4 + i];
        u32 e = (u >> 7) & 0xFFu;              // exponent field of LOW u16 as bf16
        if (e < 90u || e > 140u) outl++;       // bf16 world: ~0 ; f32 world: ~80%
    }
#pragma unroll
    for (int off = 32; off; off >>= 1) outl += __shfl_down(outl, off, 64);

    u32 v0 = mw[lane], v1 = mw[64 + lane];
    bool w4 = (v0 == 0u || v0 == 1u || v0 == 0x3F800000u) &&
              (v1 == 0u || v1 == 1u || v1 == 0x3F800000u);
    auto okh = [](u32 h) { return h == 0u || h == 1u || h == 0x3F80u; };
    bool w2 = okh(v0 & 0xFFFFu) && okh(v0 >> 16) && okh(v1 & 0xFFFFu) && okh(v1 >> 16);
    int all4 = __all(w4 ? 1 : 0);
    int all2 = __all(w2 ? 1 : 0);
    if (lane == 0) {
        flags[0] = (outl > 64) ? 1 : 0;
        flags[1] = all4 ? 0 : (all2 ? 1 : 2);
    }
}

__device__ __forceinline__ bool readM(const void* m, int s, int mwid) {
    if (mwid == 0) return ((const u32*)m)[s] != 0u;
    if (mwid == 1) return ((const u16*)m)[s] != 0u;
    return ((const u8*)m)[s] != 0u;
}
__device__ __forceinline__ u16 readW(const void* W, int s, int dt) {
    if (dt) return f2bf(((const float*)W)[s]);
    return ((const u16*)W)[s];
}

// ---------------- weight prep: masked + zero-padded [N_pad][K_pad] bf16 ----
__global__ void prep_weights(const int* __restrict__ flags, u16* __restrict__ ws,
                             const void* __restrict__ W1, const void* __restrict__ m1,
                             const void* __restrict__ W2, const void* __restrict__ m2,
                             const void* __restrict__ W3, const void* __restrict__ m3,
                             const void* __restrict__ W4, const void* __restrict__ m4)
{
    const int dt = flags[0], mwid = flags[1];
    int idx = blockIdx.x * 256 + threadIdx.x;
    if (idx < PS1) {
        int n = idx >> 10, k = idx & 1023;
        u16 v = 0;
        if (n < 1000) { int s = n * 1024 + k; if (readM(m1, s, mwid)) v = readW(W1, s, dt); }
        ws[idx] = v;
    } else if (idx < PS1 + PS2) {
        int j = idx - PS1; int n = j >> 10, k = j & 1023;
        u16 v = 0;
        if (n < 800 && k < 1000) { int s = n * 1000 + k; if (readM(m2, s, mwid)) v = readW(W2, s, dt); }
        ws[idx] = v;
    } else if (idx < PS1 + PS2 + PS3) {
        int j = idx - (PS1 + PS2); int n = j / 832, k = j - n * 832;
        u16 v = 0;
        if (n < 400 && k < 800) { int s = n * 800 + k; if (readM(m3, s, mwid)) v = readW(W3, s, dt); }
        ws[idx] = v;
    } else if (idx < PS1 + PS2 + PS3 + PS4) {
        int j = idx - (PS1 + PS2 + PS3); int n = j / 448, k = j - n * 448;
        u16 v = 0;
        if (n < 600 && k < 400) { int s = n * 400 + k; if (readM(m4, s, mwid)) v = readW(W4, s, dt); }
        ws[idx] = v;
    }
}

// ---------------- GEMM: C[M,N] = A @ Wp^T + b ------------------------------
// m97 structure: 128x128 tile, BK=64, 4 waves each 64x64, mfma 16x16x32 bf16.
// MODE 0: A is bf16. MODE 1: A is f32, staged to LDS as f32, cvt at frag build.
template <bool RELU, int MODE>
__global__ __launch_bounds__(256, 3) void gemm_bt(
    const int* __restrict__ flags,
    const void* __restrict__ Av, int strideA, int Kpad,
    const u16* __restrict__ Wp,
    const void* __restrict__ biasv, int N,
    void* __restrict__ Cv)
{
    if (flags[0] != MODE) return;

    __shared__ __attribute__((aligned(16))) char sA[32768];
    __shared__ __attribute__((aligned(16))) char sB[16384];

    const int tid  = threadIdx.x;
    const int lane = tid & 63, wid = tid >> 6;
    const int wm = wid >> 1, wn = wid & 1;
    const int bm0 = blockIdx.x * 128, bn0 = blockIdx.y * 128;
    const int q = lane >> 4, r15 = lane & 15, key = lane & 7;

    // B staging (always bf16, XOR-swizzled at 16B granularity)
    const int l3 = lane >> 3, l7 = lane & 7;
    const int kbxB = ((l7 ^ l3) << 3);
    const u16* gB = Wp + (size_t)(bn0 + wid * 32 + l3) * (size_t)Kpad + kbxB;
    char* sBw = sB + wid * 4096;

    const u16*  gA16 = nullptr;
    const float* gAf = nullptr;
    char* sAw;
    if constexpr (MODE == 0) {
        gA16 = (const u16*)Av + (size_t)(bm0 + wid * 32 + l3) * (size_t)strideA + kbxB;
        sAw = sA + wid * 4096;
    } else {
        gAf = (const float*)Av + (size_t)bm0 * (size_t)strideA;
        sAw = sA + wid * 8192;
    }

    f32x4 acc[4][4];
#pragma unroll
    for (int i = 0; i < 4; ++i)
#pragma unroll
        for (int j = 0; j < 4; ++j) acc[i][j] = (f32x4){0.f, 0.f, 0.f, 0.f};

    for (int k0 = 0; k0 < Kpad; k0 += 64) {
        if (k0) __syncthreads();
        if constexpr (MODE == 0) {
#pragma unroll
            for (int t = 0; t < 4; ++t)
                __builtin_amdgcn_global_load_lds(
                    (const __attribute__((address_space(1))) void*)(gA16 + (size_t)t * 8 * strideA),
                    (__attribute__((address_space(3))) void*)(sAw + t * 1024), 16, 0, 0);
            gA16 += 64;
        } else {
            const int l4 = lane >> 4, c = lane & 15;
#pragma unroll
            for (int t = 0; t < 8; ++t) {
                int rl = wid * 32 + t * 4 + l4;
                int cg = c ^ (rl & 15);                       // inverse swizzle at source
                const float* src = gAf + (size_t)rl * strideA + k0 + cg * 4;
                __builtin_amdgcn_global_load_lds(
                    (const __attribute__((address_space(1))) void*)src,
                    (__attribute__((address_space(3))) void*)(sAw + t * 1024), 16, 0, 0);
            }
        }
#pragma unroll
        for (int t = 0; t < 4; ++t)
            __builtin_amdgcn_global_load_lds(
                (const __attribute__((address_space(1))) void*)(gB + (size_t)t * 8 * Kpad),
                (__attribute__((address_space(3))) void*)(sBw + t * 1024), 16, 0, 0);
        gB += 64;
        __syncthreads();

#pragma unroll
        for (int kk = 0; kk < 2; ++kk) {
            bf16x8 af[4], bfr[4];
#pragma unroll
            for (int mi = 0; mi < 4; ++mi) {
                if constexpr (MODE == 0) {
                    af[mi] = *(const bf16x8*)(sA + (wm * 64 + mi * 16 + r15) * 128 +
                                              (((kk * 4 + q) ^ key) << 4));
                } else {
                    int r = wm * 64 + mi * 16 + r15;
                    int j2 = (kk * 4 + q) * 2;
                    f32x4 a0 = *(const f32x4*)(sA + r * 256 + ((j2 ^ (r & 15)) << 4));
                    f32x4 a1 = *(const f32x4*)(sA + r * 256 + (((j2 + 1) ^ (r & 15)) << 4));
                    bf16x8 tv;
                    tv[0] = (__bf16)a0[0]; tv[1] = (__bf16)a0[1];
                    tv[2] = (__bf16)a0[2]; tv[3] = (__bf16)a0[3];
                    tv[4] = (__bf16)a1[0]; tv[5] = (__bf16)a1[1];
                    tv[6] = (__bf16)a1[2]; tv[7] = (__bf16)a1[3];
                    af[mi] = tv;
                }
            }
#pragma unroll
            for (int ni = 0; ni < 4; ++ni)
                bfr[ni] = *(const bf16x8*)(sB + (wn * 64 + ni * 16 + r15) * 128 +
                                           (((kk * 4 + q) ^ key) << 4));
#pragma unroll
            for (int mi = 0; mi < 4; ++mi)
#pragma unroll
                for (int ni = 0; ni < 4; ++ni)
                    acc[mi][ni] = __builtin_amdgcn_mfma_f32_16x16x32_bf16(
                        af[mi], bfr[ni], acc[mi][ni], 0, 0, 0);
        }
    }

    // epilogue: C/D layout col=lane&15, row=(lane>>4)*4+reg  [m89/m91]
    float bv[4];
#pragma unroll
    for (int ni = 0; ni < 4; ++ni) {
        int col = bn0 + wn * 64 + ni * 16 + r15;
        bv[ni] = (col < N) ? (MODE ? ((const float*)biasv)[col] : b2f(((const u16*)biasv)[col]))
                           : 0.f;
    }
#pragma unroll
    for (int mi = 0; mi < 4; ++mi) {
#pragma unroll
        for (int ni = 0; ni < 4; ++ni) {
            int col = bn0 + wn * 64 + ni * 16 + r15;
            if (col < N) {
#pragma unroll
                for (int rr = 0; rr < 4; ++rr) {
                    int row = bm0 + wm * 64 + mi * 16 + q * 4 + rr;
                    float v = acc[mi][ni][rr] + bv[ni];
                    if (RELU) v = v > 0.f ? v : 0.f;
                    if (MODE) ((float*)Cv)[(size_t)row * N + col] = v;
                    else      ((u16*)Cv)[(size_t)row * N + col] = f2bf(v);
                }
            }
        }
    }
}

// ---------------- layer 5: [32768,600] @ [6,600]^T + b, N=6 ---------------
template <int MODE>
__global__ void layer5(const int* __restrict__ flags,
                       const void* __restrict__ h4v,
                       const void* __restrict__ W5v, const void* __restrict__ b5v,
                       const void* __restrict__ m5v,
                       void* __restrict__ out0v, void* __restrict__ out5v)
{
    if (flags[0] != MODE) return;
    const int mwid = flags[1];
    __shared__ float w[6 * 600];
    __shared__ float bs[6];
    const int tid = threadIdx.x;
    for (int i = tid; i < 3600; i += 256)
        w[i] = readM(m5v, i, mwid)
                 ? (MODE ? ((const float*)W5v)[i] : b2f(((const u16*)W5v)[i])) : 0.f;
    if (tid < 6)
        bs[tid] = MODE ? ((const float*)b5v)[tid] : b2f(((const u16*)b5v)[tid]);
    __syncthreads();

    const int wid = tid >> 6, lane = tid & 63;
    const int row = blockIdx.x * 4 + wid;

    float acc[6] = {0.f, 0.f, 0.f, 0.f, 0.f, 0.f};
    for (int p = lane; p < 300; p += 64) {
        float f0, f1;
        if (MODE) {
            float2 hv = *(const float2*)((const float*)h4v + (size_t)row * 600 + 2 * p);
            f0 = hv.x; f1 = hv.y;
        } else {
            u32 u = *(const u32*)((const u16*)h4v + (size_t)row * 600 + 2 * p);
            f0 = b2f((u16)(u & 0xffff)); f1 = b2f((u16)(u >> 16));
        }
        int k = 2 * p;
#pragma unroll
        for (int j = 0; j < 6; ++j) {
            float2 wv = *(const float2*)&w[j * 600 + k];
            acc[j] += f0 * wv.x + f1 * wv.y;
        }
    }
#pragma unroll
    for (int j = 0; j < 6; ++j)
#pragma unroll
        for (int off = 32; off > 0; off >>= 1)
            acc[j] += __shfl_down(acc[j], off, 64);

    if (lane == 0) {
#pragma unroll
        for (int j = 0; j < 6; ++j) {
            float v = acc[j] + bs[j];
            if (MODE) {
                ((float*)out0v)[(size_t)row * 6 + j] = v;
                ((float*)out5v)[(size_t)row * 6 + j] = v;
            } else {
                u16 b = f2bf(v);
                ((u16*)out0v)[(size_t)row * 6 + j] = b;
                ((u16*)out5v)[(size_t)row * 6 + j] = b;
            }
        }
    }
}

// ---------------- launch ---------------------------------------------------
extern "C" void kernel_launch(void* const* d_in, const int* in_sizes, int n_in,
                              void* d_out, int out_size, void* d_ws, size_t ws_size,
                              hipStream_t stream) {
    int* flags = (int*)d_ws;
    u16* wsW   = (u16*)d_ws + WS_OFF;

    detect_kernel<<<1, 64, 0, stream>>>(flags, (const u32*)d_in[0], (const u32*)d_in[3]);
    prep_weights<<<10464, 256, 0, stream>>>(flags, wsW,
                                            d_in[1], d_in[3], d_in[4], d_in[6],
                                            d_in[7], d_in[9], d_in[10], d_in[12]);

    // d_out element offsets: h5a=0, h1=196608, h2=32964608, h3=59179008,
    // h4=72286208, h5b=91947008  (total 92143616) — element-indexed, dtype per mode
    u16*   o16 = (u16*)d_out;
    float* o32 = (float*)d_out;

    // L1
    gemm_bt<true, 0><<<dim3(256, 8), 256, 0, stream>>>(flags, d_in[0], 1024, 1024,
                                                       wsW + OFF_W1, d_in[2], 1000, o16 + 196608);
    gemm_bt<true, 1><<<dim3(256, 8), 256, 0, stream>>>(flags, d_in[0], 1024, 1024,
                                                       wsW + OFF_W1, d_in[2], 1000, o32 + 196608);
    // L2 (K 1000 -> 1024, zero-padded weights absorb A spill)
    gemm_bt<true, 0><<<dim3(256, 7), 256, 0, stream>>>(flags, o16 + 196608, 1000, 1024,
                                                       wsW + OFF_W2, d_in[5], 800, o16 + 32964608);
    gemm_bt<true, 1><<<dim3(256, 7), 256, 0, stream>>>(flags, o32 + 196608, 1000, 1024,
                                                       wsW + OFF_W2, d_in[5], 800, o32 + 32964608);
    // L3 (K 800 -> 832)
    gemm_bt<true, 0><<<dim3(256, 4), 256, 0, stream>>>(flags, o16 + 32964608, 800, 832,
                                                       wsW + OFF_W3, d_in[8], 400, o16 + 59179008);
    gemm_bt<true, 1><<<dim3(256, 4), 256, 0, stream>>>(flags, o32 + 32964608, 800, 832,
                                                       wsW + OFF_W3, d_in[8], 400, o32 + 59179008);
    // L4 (K 400 -> 448, no relu)
    gemm_bt<false, 0><<<dim3(256, 5), 256, 0, stream>>>(flags, o16 + 59179008, 400, 448,
                                                        wsW + OFF_W4, d_in[11], 600, o16 + 72286208);
    gemm_bt<false, 1><<<dim3(256, 5), 256, 0, stream>>>(flags, o32 + 59179008, 400, 448,
                                                        wsW + OFF_W4, d_in[11], 600, o32 + 72286208);
    // L5
    layer5<0><<<8192, 256, 0, stream>>>(flags, o16 + 72286208, d_in[13], d_in[14], d_in[15],
                                        o16, o16 + 91947008);
    layer5<1><<<8192, 256, 0, stream>>>(flags, o32 + 72286208, d_in[13], d_in[14], d_in[15],
                                        o32, o32 + 91947008);
}